// Round 4
// baseline (502.181 us; speedup 1.0000x reference)
//
#include <hip/hip_runtime.h>
#include <stdint.h>

#define LEVELS    16
#define TSIZE     524288
#define TMASK     (TSIZE - 1)
#define PRIME1    2654435761u
#define NBINS     65536          // 8 bits per dim, Morton-interleaved
#define NCHUNK    256            // scan chunks of 256 bins

typedef float f32x4 __attribute__((ext_vector_type(4)));  // clang vector: valid for nontemporal builtins

// floor(16 * 2^(l/3)) — canonical instant-NGP ladder (N_MIN=16, N_MAX=512, 16 levels)
__device__ __constant__ float c_res[LEVELS] = {
    16.f, 20.f, 25.f, 32.f, 40.f, 50.f, 64.f, 80.f,
    101.f, 128.f, 161.f, 203.f, 256.f, 322.f, 406.f, 512.f
};

__device__ __forceinline__ uint32_t morton_key(float2 p) {
    float fx = fminf(fmaxf(p.x, 0.f), 0.999999f);
    float fy = fminf(fmaxf(p.y, 0.f), 0.999999f);
    uint32_t x = (uint32_t)(fx * 256.f);
    uint32_t y = (uint32_t)(fy * 256.f);
    x = (x | (x << 4)) & 0x0F0Fu; x = (x | (x << 2)) & 0x3333u; x = (x | (x << 1)) & 0x5555u;
    y = (y | (y << 4)) & 0x0F0Fu; y = (y | (y << 2)) & 0x3333u; y = (y | (y << 1)) & 0x5555u;
    return x | (y << 1);
}

// ---- core per-point computation (identical arithmetic to R0 kernel) ----
__device__ __forceinline__ void hashenc_point(float2 p, const float* __restrict__ tables,
                                              float* __restrict__ outline) {
    float acc0[LEVELS], acc1[LEVELS];
#pragma unroll
    for (int l = 0; l < LEVELS; ++l) {
        float r  = c_res[l];
        float s0 = p.x * r;
        float s1 = p.y * r;
        float g0 = floorf(s0);
        float g1 = floorf(s1);
        uint32_t i0 = (uint32_t)(int)g0;
        uint32_t i1 = (uint32_t)(int)g1;
        uint32_t hy0 = i1 * PRIME1;
        uint32_t hy1 = (i1 + 1u) * PRIME1;
        uint32_t h00 = ( i0       ^ hy0) & TMASK;
        uint32_t h10 = ((i0 + 1u) ^ hy0) & TMASK;
        uint32_t h01 = ( i0       ^ hy1) & TMASK;
        uint32_t h11 = ((i0 + 1u) ^ hy1) & TMASK;

        const float2* tab = reinterpret_cast<const float2*>(tables) + (size_t)l * TSIZE;
        float2 t00 = tab[h00];
        float2 t10 = tab[h10];
        float2 t01 = tab[h01];
        float2 t11 = tab[h11];

        float wx0 = fabsf(s0 - g0);
        float wx1 = fabsf(s0 - (g0 + 1.f));
        float wy0 = fabsf(s1 - g1);
        float wy1 = fabsf(s1 - (g1 + 1.f));
        float w00 = wx0 * wy0, w10 = wx1 * wy0, w01 = wx0 * wy1, w11 = wx1 * wy1;

        acc0[l] = w00 * t00.x + w10 * t10.x + w01 * t01.x + w11 * t11.x;
        acc1[l] = w00 * t00.y + w10 * t10.y + w01 * t01.y + w11 * t11.y;
    }
    // scattered 128B line: bypass L2 (keep it for table gathers)
    f32x4* o = reinterpret_cast<f32x4*>(outline);
    f32x4 v;
    v = (f32x4){acc0[0],  acc0[1],  acc0[2],  acc0[3]};  __builtin_nontemporal_store(v, &o[0]);
    v = (f32x4){acc0[4],  acc0[5],  acc0[6],  acc0[7]};  __builtin_nontemporal_store(v, &o[1]);
    v = (f32x4){acc0[8],  acc0[9],  acc0[10], acc0[11]}; __builtin_nontemporal_store(v, &o[2]);
    v = (f32x4){acc0[12], acc0[13], acc0[14], acc0[15]}; __builtin_nontemporal_store(v, &o[3]);
    v = (f32x4){acc1[0],  acc1[1],  acc1[2],  acc1[3]};  __builtin_nontemporal_store(v, &o[4]);
    v = (f32x4){acc1[4],  acc1[5],  acc1[6],  acc1[7]};  __builtin_nontemporal_store(v, &o[5]);
    v = (f32x4){acc1[8],  acc1[9],  acc1[10], acc1[11]}; __builtin_nontemporal_store(v, &o[6]);
    v = (f32x4){acc1[12], acc1[13], acc1[14], acc1[15]}; __builtin_nontemporal_store(v, &o[7]);
}

// ---- sort passes ----
__global__ __launch_bounds__(256)
void zero_hist_kernel(uint32_t* __restrict__ hist) {
    hist[blockIdx.x * 256 + threadIdx.x] = 0u;
}

__global__ __launch_bounds__(256)
void hist_kernel(const float* __restrict__ x, uint32_t* __restrict__ hist, int npts) {
    int n = blockIdx.x * 256 + threadIdx.x;
    if (n >= npts) return;
    float2 p = reinterpret_cast<const float2*>(x)[n];
    atomicAdd(&hist[morton_key(p)], 1u);
}

// scan1: 256 blocks; block b converts hist[b*256 .. b*256+255] to a
// block-local EXCLUSIVE scan and writes the chunk total to totals[b].
__global__ __launch_bounds__(256)
void scan1_kernel(uint32_t* __restrict__ hist, uint32_t* __restrict__ totals) {
    __shared__ uint32_t s[NCHUNK];
    int t = threadIdx.x;
    int base = blockIdx.x * NCHUNK;
    uint32_t v = hist[base + t];
    s[t] = v;
    __syncthreads();
    // Hillis-Steele inclusive scan over 256
    for (int off = 1; off < NCHUNK; off <<= 1) {
        uint32_t u = (t >= off) ? s[t - off] : 0u;
        __syncthreads();
        s[t] += u;
        __syncthreads();
    }
    hist[base + t] = s[t] - v;   // exclusive
    if (t == NCHUNK - 1) totals[blockIdx.x] = s[t];
}

// scan2: single block; exclusive scan of the 256 chunk totals in place.
__global__ __launch_bounds__(256)
void scan2_kernel(uint32_t* __restrict__ totals) {
    __shared__ uint32_t s[NCHUNK];
    int t = threadIdx.x;
    uint32_t v = totals[t];
    s[t] = v;
    __syncthreads();
    for (int off = 1; off < NCHUNK; off <<= 1) {
        uint32_t u = (t >= off) ? s[t - off] : 0u;
        __syncthreads();
        s[t] += u;
        __syncthreads();
    }
    totals[t] = s[t] - v;        // exclusive chunk base
}

// scatter: pos = chunk_base[bin>>8] + within-chunk exclusive base + atomic rank
__global__ __launch_bounds__(256)
void scatter_kernel(const float* __restrict__ x, uint32_t* __restrict__ hist,
                    const uint32_t* __restrict__ totals,
                    uint32_t* __restrict__ perm, float2* __restrict__ sx, int npts) {
    int n = blockIdx.x * 256 + threadIdx.x;
    if (n >= npts) return;
    float2 p = reinterpret_cast<const float2*>(x)[n];
    uint32_t bin = morton_key(p);
    uint32_t pos = totals[bin >> 8] + atomicAdd(&hist[bin], 1u);
    perm[pos] = (uint32_t)n;
    sx[pos] = p;
}

// ---- main kernels ----
__global__ __launch_bounds__(256)
void hashenc_sorted_kernel(const uint32_t* __restrict__ perm,
                           const float2* __restrict__ sx,
                           const float* __restrict__ tables,
                           float* __restrict__ out, int npts) {
    int i = blockIdx.x * 256 + threadIdx.x;
    if (i >= npts) return;
    uint32_t n = __builtin_nontemporal_load(&perm[i]);
    float2 p;
    p.x = __builtin_nontemporal_load(&sx[i].x);
    p.y = __builtin_nontemporal_load(&sx[i].y);
    hashenc_point(p, tables, out + (size_t)n * 32);
}

__global__ __launch_bounds__(256)
void hashenc_kernel(const float* __restrict__ x,
                    const float* __restrict__ tables,
                    float* __restrict__ out, int npts) {
    int n = blockIdx.x * 256 + threadIdx.x;
    if (n >= npts) return;
    float2 p = reinterpret_cast<const float2*>(x)[n];
    hashenc_point(p, tables, out + (size_t)n * 32);
}

extern "C" void kernel_launch(void* const* d_in, const int* in_sizes, int n_in,
                              void* d_out, int out_size, void* d_ws, size_t ws_size,
                              hipStream_t stream) {
    const float* x      = (const float*)d_in[0];
    const float* tables = (const float*)d_in[1];
    float* out          = (float*)d_out;
    int npts = in_sizes[0] / 2;
    int blocks = (npts + 255) / 256;

    size_t hist_bytes   = (size_t)NBINS * 4;
    size_t totals_bytes = (size_t)NCHUNK * 4;
    size_t perm_bytes   = (size_t)npts * 4;
    size_t sx_bytes     = (size_t)npts * 8;
    size_t needed = hist_bytes + totals_bytes + perm_bytes + sx_bytes;

    if (ws_size < needed) {
        hashenc_kernel<<<blocks, 256, 0, stream>>>(x, tables, out, npts);
        return;
    }

    uint32_t* hist   = (uint32_t*)d_ws;
    uint32_t* totals = (uint32_t*)((char*)d_ws + hist_bytes);
    uint32_t* perm   = (uint32_t*)((char*)d_ws + hist_bytes + totals_bytes);
    float2*   sx     = (float2*)((char*)d_ws + hist_bytes + totals_bytes + perm_bytes);

    zero_hist_kernel<<<NBINS / 256, 256, 0, stream>>>(hist);
    hist_kernel<<<blocks, 256, 0, stream>>>(x, hist, npts);
    scan1_kernel<<<NBINS / NCHUNK, 256, 0, stream>>>(hist, totals);
    scan2_kernel<<<1, 256, 0, stream>>>(totals);
    scatter_kernel<<<blocks, 256, 0, stream>>>(x, hist, totals, perm, sx, npts);
    hashenc_sorted_kernel<<<blocks, 256, 0, stream>>>(perm, sx, tables, out, npts);
}

// Round 5
// 337.047 us; speedup vs baseline: 1.4899x; 1.4899x over previous
//
#include <hip/hip_runtime.h>
#include <stdint.h>

#define LEVELS    16
#define TSIZE     524288
#define TMASK     (TSIZE - 1)
#define PRIME1    2654435761u
#define NBINS     65536          // 8 bits per dim, Morton-interleaved
#define NCHUNK    256            // scan chunks of 256 bins
#define ROWF      33             // LDS row stride in floats (32 + 1 pad)

typedef float f32x4 __attribute__((ext_vector_type(4)));

// floor(16 * 2^(l/3)) — canonical instant-NGP ladder (N_MIN=16, N_MAX=512, 16 levels)
__device__ __constant__ float c_res[LEVELS] = {
    16.f, 20.f, 25.f, 32.f, 40.f, 50.f, 64.f, 80.f,
    101.f, 128.f, 161.f, 203.f, 256.f, 322.f, 406.f, 512.f
};

__device__ __forceinline__ uint32_t morton_key(float2 p) {
    float fx = fminf(fmaxf(p.x, 0.f), 0.999999f);
    float fy = fminf(fmaxf(p.y, 0.f), 0.999999f);
    uint32_t x = (uint32_t)(fx * 256.f);
    uint32_t y = (uint32_t)(fy * 256.f);
    x = (x | (x << 4)) & 0x0F0Fu; x = (x | (x << 2)) & 0x3333u; x = (x | (x << 1)) & 0x5555u;
    y = (y | (y << 4)) & 0x0F0Fu; y = (y | (y << 2)) & 0x3333u; y = (y | (y << 1)) & 0x5555u;
    return x | (y << 1);
}

// ---- core per-point computation (identical arithmetic to R0 kernel) ----
__device__ __forceinline__ void hashenc_accum(float2 p, const float* __restrict__ tables,
                                              float* acc0, float* acc1) {
#pragma unroll
    for (int l = 0; l < LEVELS; ++l) {
        float r  = c_res[l];
        float s0 = p.x * r;
        float s1 = p.y * r;
        float g0 = floorf(s0);
        float g1 = floorf(s1);
        uint32_t i0 = (uint32_t)(int)g0;
        uint32_t i1 = (uint32_t)(int)g1;
        uint32_t hy0 = i1 * PRIME1;
        uint32_t hy1 = (i1 + 1u) * PRIME1;
        uint32_t h00 = ( i0       ^ hy0) & TMASK;
        uint32_t h10 = ((i0 + 1u) ^ hy0) & TMASK;
        uint32_t h01 = ( i0       ^ hy1) & TMASK;
        uint32_t h11 = ((i0 + 1u) ^ hy1) & TMASK;

        const float2* tab = reinterpret_cast<const float2*>(tables) + (size_t)l * TSIZE;
        float2 t00 = tab[h00];
        float2 t10 = tab[h10];
        float2 t01 = tab[h01];
        float2 t11 = tab[h11];

        float wx0 = fabsf(s0 - g0);
        float wx1 = fabsf(s0 - (g0 + 1.f));
        float wy0 = fabsf(s1 - g1);
        float wy1 = fabsf(s1 - (g1 + 1.f));
        float w00 = wx0 * wy0, w10 = wx1 * wy0, w01 = wx0 * wy1, w11 = wx1 * wy1;

        acc0[l] = w00 * t00.x + w10 * t10.x + w01 * t01.x + w11 * t11.x;
        acc1[l] = w00 * t00.y + w10 * t10.y + w01 * t01.y + w11 * t11.y;
    }
}

// ---- sort passes ----
__global__ __launch_bounds__(256)
void zero_hist_kernel(uint32_t* __restrict__ hist) {
    hist[blockIdx.x * 256 + threadIdx.x] = 0u;
}

__global__ __launch_bounds__(256)
void hist_kernel(const float* __restrict__ x, uint32_t* __restrict__ hist, int npts) {
    int n = blockIdx.x * 256 + threadIdx.x;
    if (n >= npts) return;
    float2 p = reinterpret_cast<const float2*>(x)[n];
    atomicAdd(&hist[morton_key(p)], 1u);
}

__global__ __launch_bounds__(256)
void scan1_kernel(uint32_t* __restrict__ hist, uint32_t* __restrict__ totals) {
    __shared__ uint32_t s[NCHUNK];
    int t = threadIdx.x;
    int base = blockIdx.x * NCHUNK;
    uint32_t v = hist[base + t];
    s[t] = v;
    __syncthreads();
    for (int off = 1; off < NCHUNK; off <<= 1) {
        uint32_t u = (t >= off) ? s[t - off] : 0u;
        __syncthreads();
        s[t] += u;
        __syncthreads();
    }
    hist[base + t] = s[t] - v;   // exclusive
    if (t == NCHUNK - 1) totals[blockIdx.x] = s[t];
}

__global__ __launch_bounds__(256)
void scan2_kernel(uint32_t* __restrict__ totals) {
    __shared__ uint32_t s[NCHUNK];
    int t = threadIdx.x;
    uint32_t v = totals[t];
    s[t] = v;
    __syncthreads();
    for (int off = 1; off < NCHUNK; off <<= 1) {
        uint32_t u = (t >= off) ? s[t - off] : 0u;
        __syncthreads();
        s[t] += u;
        __syncthreads();
    }
    totals[t] = s[t] - v;        // exclusive chunk base
}

__global__ __launch_bounds__(256)
void scatter_kernel(const float* __restrict__ x, uint32_t* __restrict__ hist,
                    const uint32_t* __restrict__ totals,
                    uint32_t* __restrict__ perm, float2* __restrict__ sx, int npts) {
    int n = blockIdx.x * 256 + threadIdx.x;
    if (n >= npts) return;
    float2 p = reinterpret_cast<const float2*>(x)[n];
    uint32_t bin = morton_key(p);
    uint32_t pos = totals[bin >> 8] + atomicAdd(&hist[bin], 1u);
    perm[pos] = (uint32_t)n;
    sx[pos] = p;
}

// ---- main kernel: sorted gather + LDS-transposed coalesced store ----
__global__ __launch_bounds__(256)
void hashenc_sorted_kernel(const uint32_t* __restrict__ perm,
                           const float2* __restrict__ sx,
                           const float* __restrict__ tables,
                           float* __restrict__ out, int npts) {
    __shared__ float   lds[256 * ROWF];
    __shared__ uint32_t lperm[256];

    int t = threadIdx.x;
    int i = blockIdx.x * 256 + t;

    lperm[t] = 0xFFFFFFFFu;
    if (i < npts) {
        uint32_t n = __builtin_nontemporal_load(&perm[i]);
        float2 p;
        p.x = __builtin_nontemporal_load(&sx[i].x);
        p.y = __builtin_nontemporal_load(&sx[i].y);

        float acc0[LEVELS], acc1[LEVELS];
        hashenc_accum(p, tables, acc0, acc1);

        lperm[t] = n;
        float* row = &lds[t * ROWF];
#pragma unroll
        for (int l = 0; l < LEVELS; ++l) row[l] = acc0[l];
#pragma unroll
        for (int l = 0; l < LEVELS; ++l) row[16 + l] = acc1[l];
    }
    __syncthreads();

    // wave-local transpose: 8 lanes cooperatively write each point's 128B line.
    int sub = t & 63;          // lane in wave
    int wb  = t & ~63;         // wave's base thread
    int c   = sub & 7;         // 16B chunk index within a point's line
    int pr  = sub >> 3;        // point sub-index 0..7
#pragma unroll
    for (int it = 0; it < 8; ++it) {
        int pp = wb + pr + it * 8;             // point slot in block
        uint32_t nn = lperm[pp];
        if (nn != 0xFFFFFFFFu) {
            f32x4 v = *reinterpret_cast<const f32x4*>(&lds[pp * ROWF + c * 4]);
            __builtin_nontemporal_store(v,
                reinterpret_cast<f32x4*>(out + (size_t)nn * 32 + c * 4));
        }
    }
}

// unsorted fallback (small ws)
__global__ __launch_bounds__(256)
void hashenc_kernel(const float* __restrict__ x,
                    const float* __restrict__ tables,
                    float* __restrict__ out, int npts) {
    int n = blockIdx.x * 256 + threadIdx.x;
    if (n >= npts) return;
    float2 p = reinterpret_cast<const float2*>(x)[n];
    float acc0[LEVELS], acc1[LEVELS];
    hashenc_accum(p, tables, acc0, acc1);
    float* o = out + (size_t)n * 32;
#pragma unroll
    for (int l = 0; l < LEVELS; ++l) o[l] = acc0[l];
#pragma unroll
    for (int l = 0; l < LEVELS; ++l) o[16 + l] = acc1[l];
}

extern "C" void kernel_launch(void* const* d_in, const int* in_sizes, int n_in,
                              void* d_out, int out_size, void* d_ws, size_t ws_size,
                              hipStream_t stream) {
    const float* x      = (const float*)d_in[0];
    const float* tables = (const float*)d_in[1];
    float* out          = (float*)d_out;
    int npts = in_sizes[0] / 2;
    int blocks = (npts + 255) / 256;

    size_t hist_bytes   = (size_t)NBINS * 4;
    size_t totals_bytes = (size_t)NCHUNK * 4;
    size_t perm_bytes   = (size_t)npts * 4;
    size_t sx_bytes     = (size_t)npts * 8;
    size_t needed = hist_bytes + totals_bytes + perm_bytes + sx_bytes;

    if (ws_size < needed) {
        hashenc_kernel<<<blocks, 256, 0, stream>>>(x, tables, out, npts);
        return;
    }

    uint32_t* hist   = (uint32_t*)d_ws;
    uint32_t* totals = (uint32_t*)((char*)d_ws + hist_bytes);
    uint32_t* perm   = (uint32_t*)((char*)d_ws + hist_bytes + totals_bytes);
    float2*   sx     = (float2*)((char*)d_ws + hist_bytes + totals_bytes + perm_bytes);

    zero_hist_kernel<<<NBINS / 256, 256, 0, stream>>>(hist);
    hist_kernel<<<blocks, 256, 0, stream>>>(x, hist, npts);
    scan1_kernel<<<NBINS / NCHUNK, 256, 0, stream>>>(hist, totals);
    scan2_kernel<<<1, 256, 0, stream>>>(totals);
    scatter_kernel<<<blocks, 256, 0, stream>>>(x, hist, totals, perm, sx, npts);
    hashenc_sorted_kernel<<<blocks, 256, 0, stream>>>(perm, sx, tables, out, npts);
}